// Round 1
// baseline (4224.781 us; speedup 1.0000x reference)
//
#include <hip/hip_runtime.h>

#define NN 50000
#define NE 800000
#define NR 8
#define EMBD 512
#define PROJD 256
#define HIDD 256
#define OUTD 200
#define NSEG (NN * NR)

// ---------------- CSR build ----------------

__global__ void count_edges(const int* __restrict__ dst, const int* __restrict__ rel,
                            int* __restrict__ cnt, int E) {
    int e = blockIdx.x * 256 + threadIdx.x;
    if (e >= E) return;
    atomicAdd(&cnt[dst[e] * NR + rel[e]], 1);
}

__global__ __launch_bounds__(512) void scan1(const int* __restrict__ cnt, int* __restrict__ offs,
                                             int* __restrict__ bsums, int n) {
    __shared__ int sm[512];
    int tid = threadIdx.x;
    int g = blockIdx.x * 512 + tid;
    int v = (g < n) ? cnt[g] : 0;
    sm[tid] = v;
    __syncthreads();
    for (int o = 1; o < 512; o <<= 1) {
        int t = (tid >= o) ? sm[tid - o] : 0;
        __syncthreads();
        sm[tid] += t;
        __syncthreads();
    }
    if (g < n) offs[g] = sm[tid] - v;  // exclusive within block
    if (tid == 511) bsums[blockIdx.x] = sm[511];
}

__global__ __launch_bounds__(1024) void scan2(const int* __restrict__ bsums, int* __restrict__ bpref, int nb) {
    __shared__ int sm[1024];
    int tid = threadIdx.x;
    int v = (tid < nb) ? bsums[tid] : 0;
    sm[tid] = v;
    __syncthreads();
    for (int o = 1; o < 1024; o <<= 1) {
        int t = (tid >= o) ? sm[tid - o] : 0;
        __syncthreads();
        sm[tid] += t;
        __syncthreads();
    }
    if (tid < nb) bpref[tid] = sm[tid] - v;  // exclusive
}

__global__ __launch_bounds__(512) void scan3(int* __restrict__ offs, int* __restrict__ cursor,
                                             const int* __restrict__ bpref, int n, int total) {
    int g = blockIdx.x * 512 + threadIdx.x;
    if (g < n) {
        int v = offs[g] + bpref[blockIdx.x];
        offs[g] = v;
        cursor[g] = v;
    }
    if (g == 0) offs[n] = total;
}

__global__ void make_inv(const int* __restrict__ cnt, float* __restrict__ inv, int n) {
    int i = blockIdx.x * 256 + threadIdx.x;
    if (i >= n) return;
    int c = cnt[i];
    inv[i] = 1.0f / (float)(c > 1 ? c : 1);
}

__global__ void scatter_edges(const int* __restrict__ dst, const int* __restrict__ rel,
                              const int* __restrict__ src, int* __restrict__ cursor,
                              int* __restrict__ csr, int E) {
    int e = blockIdx.x * 256 + threadIdx.x;
    if (e >= E) return;
    int seg = dst[e] * NR + rel[e];
    int pos = atomicAdd(&cursor[seg], 1);
    csr[pos] = src[e];
}

// ---------------- segment mean (per relation): m[d,:] = mean of x[src,:] ----------------
// block = 256 threads = 4 waves; each wave handles one destination d, float4 channels.

__global__ __launch_bounds__(256) void segmean4(const float* __restrict__ x, const int* __restrict__ csr,
                                                const int* __restrict__ offs, const float* __restrict__ invc,
                                                float* __restrict__ m, int r) {
    int wave = threadIdx.x >> 6;
    int lane = threadIdx.x & 63;
    int d = blockIdx.x * 4 + wave;
    if (d >= NN) return;
    int seg = d * NR + r;
    int o0 = offs[seg], o1 = offs[seg + 1];
    float4 s = make_float4(0.f, 0.f, 0.f, 0.f);
    for (int j = o0; j < o1; ++j) {
        const float4* row = reinterpret_cast<const float4*>(x + (size_t)csr[j] * PROJD);
        float4 v = row[lane];
        s.x += v.x; s.y += v.y; s.z += v.z; s.w += v.w;
    }
    float ic = invc[seg];
    s.x *= ic; s.y *= ic; s.z *= ic; s.w *= ic;
    reinterpret_cast<float4*>(m + (size_t)d * PROJD)[lane] = s;
}

// ---------------- fp32 tiled GEMM: C[M,N] (+)= A[M,K] @ B[K,N] (+bias)(relu)(row-scatter) ----------------
// 64x64 tile, BK=32, 256 threads, 4x4 microtile.

template <bool ACCUM, bool HAS_BIAS, bool RELU, bool SCATTER>
__global__ __launch_bounds__(256) void gemm_f32(const float* __restrict__ A, int lda,
                                                const float* __restrict__ B, int ldb,
                                                float* C, int ldc,
                                                const float* __restrict__ bias,
                                                const int* __restrict__ sidx,
                                                int M, int N, int K) {
    __shared__ __align__(16) float As[32][68];  // [k][m], padded stride
    __shared__ __align__(16) float Bs[32][68];  // [k][n]
    const int tid = threadIdx.x;
    const int tx = tid & 15, ty = tid >> 4;
    const int m0 = blockIdx.y * 64;
    const int n0 = blockIdx.x * 64;
    float acc[4][4] = {};
    const int kTiles = K >> 5;
    for (int kt = 0; kt < kTiles; ++kt) {
        const int k0 = kt << 5;
#pragma unroll
        for (int l = 0; l < 2; ++l) {  // A: 64 rows x 32 cols = 512 float4 slots
            int s = tid + l * 256;
            int row = s >> 3;
            int c4 = s & 7;
            float4 v = make_float4(0.f, 0.f, 0.f, 0.f);
            int gr = m0 + row;
            if (gr < M) v = *reinterpret_cast<const float4*>(A + (size_t)gr * lda + k0 + (c4 << 2));
            As[(c4 << 2) + 0][row] = v.x;
            As[(c4 << 2) + 1][row] = v.y;
            As[(c4 << 2) + 2][row] = v.z;
            As[(c4 << 2) + 3][row] = v.w;
        }
#pragma unroll
        for (int l = 0; l < 2; ++l) {  // B: 32 rows x 64 cols = 512 float4 slots
            int s = tid + l * 256;
            int row = s >> 4;
            int c4 = s & 15;
            int gc = n0 + (c4 << 2);
            float4 v = make_float4(0.f, 0.f, 0.f, 0.f);
            if (gc < N) v = *reinterpret_cast<const float4*>(B + (size_t)(k0 + row) * ldb + gc);
            *reinterpret_cast<float4*>(&Bs[row][c4 << 2]) = v;
        }
        __syncthreads();
#pragma unroll
        for (int kk = 0; kk < 32; ++kk) {
            float4 av = *reinterpret_cast<const float4*>(&As[kk][ty << 2]);
            float4 bv = *reinterpret_cast<const float4*>(&Bs[kk][tx << 2]);
            float a_[4] = {av.x, av.y, av.z, av.w};
            float b_[4] = {bv.x, bv.y, bv.z, bv.w};
#pragma unroll
            for (int i = 0; i < 4; ++i)
#pragma unroll
                for (int j = 0; j < 4; ++j) acc[i][j] += a_[i] * b_[j];
        }
        __syncthreads();
    }
#pragma unroll
    for (int i = 0; i < 4; ++i) {
        int r = m0 + (ty << 2) + i;
        if (r >= M) continue;
        int ro = SCATTER ? sidx[r] : r;
#pragma unroll
        for (int j = 0; j < 4; ++j) {
            int c = n0 + (tx << 2) + j;
            if (c >= N) continue;
            float v = acc[i][j];
            if (ACCUM) v += C[(size_t)ro * ldc + c];
            if (HAS_BIAS) v += bias[c];
            if (RELU) v = fmaxf(v, 0.f);
            C[(size_t)ro * ldc + c] = v;
        }
    }
}

// ---------------- DistMult decoder: one wave per triple ----------------

__global__ __launch_bounds__(256) void decoder(const float* __restrict__ out, const float* __restrict__ rel_emb,
                                               const int* __restrict__ src, const int* __restrict__ dst,
                                               const int* __restrict__ rel, const int* __restrict__ nsrc,
                                               const int* __restrict__ ndst, const int* __restrict__ nrel,
                                               float* __restrict__ scores, int E) {
    int wid = (blockIdx.x * 256 + threadIdx.x) >> 6;
    int lane = threadIdx.x & 63;
    if (wid >= 2 * E) return;
    int s, o, r;
    if (wid < E) {
        s = src[wid]; o = dst[wid]; r = rel[wid];
    } else {
        s = nsrc[wid - E]; o = ndst[wid - E]; r = nrel[wid - E];
    }
    const float* ps = out + (size_t)s * OUTD;
    const float* po = out + (size_t)o * OUTD;
    const float* pr = rel_emb + (size_t)r * OUTD;
    float acc = 0.f;
    for (int c = lane; c < OUTD; c += 64) acc += ps[c] * pr[c] * po[c];
#pragma unroll
    for (int off = 32; off > 0; off >>= 1) acc += __shfl_down(acc, off);
    if (lane == 0) scores[wid] = acc;
}

// ---------------- host ----------------

extern "C" void kernel_launch(void* const* d_in, const int* in_sizes, int n_in,
                              void* d_out, int out_size, void* d_ws, size_t ws_size,
                              hipStream_t stream) {
    const float* emb   = (const float*)d_in[0];
    const int*   nidx  = (const int*)d_in[1];
    const int*   src   = (const int*)d_in[2];
    const int*   dst   = (const int*)d_in[3];
    const int*   rel   = (const int*)d_in[4];
    const int*   nsrc  = (const int*)d_in[5];
    const int*   ndst  = (const int*)d_in[6];
    const int*   nrel  = (const int*)d_in[7];
    const float* Wp    = (const float*)d_in[8];
    const float* bp    = (const float*)d_in[9];
    const float* W0    = (const float*)d_in[10];
    const float* root0 = (const float*)d_in[11];
    const float* b0    = (const float*)d_in[12];
    const float* W1    = (const float*)d_in[13];
    const float* root1 = (const float*)d_in[14];
    const float* b1    = (const float*)d_in[15];
    const float* W2    = (const float*)d_in[16];
    const float* root2 = (const float*)d_in[17];
    const float* b2    = (const float*)d_in[18];
    const float* rele  = (const float*)d_in[19];

    float* out    = (float*)d_out;                       // [NN, OUTD]
    float* scores = out + (size_t)NN * OUTD;             // [2*NE]

    size_t off = 0;
    auto alloc = [&](size_t bytes) -> void* {
        void* p = (char*)d_ws + off;
        off += (bytes + 255) & ~(size_t)255;
        return p;
    };
    float* bufA   = (float*)alloc((size_t)NN * PROJD * 4);  // proj out / L1 out
    float* bufB   = (float*)alloc((size_t)NN * PROJD * 4);  // L0 out
    float* mbuf   = (float*)alloc((size_t)NN * PROJD * 4);  // per-relation mean
    int*   cnt    = (int*)alloc((size_t)NSEG * 4);
    float* invc   = (float*)alloc((size_t)NSEG * 4);
    int*   offs   = (int*)alloc((size_t)(NSEG + 1) * 4);
    int*   cursor = (int*)alloc((size_t)NSEG * 4);
    int*   csr    = (int*)alloc((size_t)NE * 4);
    int*   bsums  = (int*)alloc(1024 * 4);
    int*   bpref  = (int*)alloc(1024 * 4);
    (void)ws_size; (void)n_in; (void)in_sizes; (void)out_size;

    // --- CSR build (reused across all 3 layers) ---
    hipMemsetAsync(cnt, 0, (size_t)NSEG * 4, stream);
    count_edges<<<(NE + 255) / 256, 256, 0, stream>>>(dst, rel, cnt, NE);
    const int NB = (NSEG + 511) / 512;  // 782 <= 1024
    scan1<<<NB, 512, 0, stream>>>(cnt, offs, bsums, NSEG);
    scan2<<<1, 1024, 0, stream>>>(bsums, bpref, NB);
    scan3<<<NB, 512, 0, stream>>>(offs, cursor, bpref, NSEG, NE);
    make_inv<<<(NSEG + 255) / 256, 256, 0, stream>>>(cnt, invc, NSEG);
    scatter_edges<<<(NE + 255) / 256, 256, 0, stream>>>(dst, rel, src, cursor, csr, NE);

    // --- projection: bufA[nidx[i],:] = emb[i,:] @ Wp + bp ---
    {
        dim3 g((PROJD + 63) / 64, (NN + 63) / 64);
        gemm_f32<false, true, false, true><<<g, 256, 0, stream>>>(
            emb, EMBD, Wp, PROJD, bufA, PROJD, bp, nidx, NN, PROJD, EMBD);
    }

    // --- RGCN layers ---
    auto layer = [&](const float* xin, float* xout, const float* W, const float* root,
                     const float* bias, int outd, bool relu) {
        dim3 g((outd + 63) / 64, (NN + 63) / 64);
        gemm_f32<false, true, false, false><<<g, 256, 0, stream>>>(
            xin, PROJD, root, outd, xout, outd, bias, nullptr, NN, outd, PROJD);
        for (int r = 0; r < NR; ++r) {
            segmean4<<<(NN + 3) / 4, 256, 0, stream>>>(xin, csr, offs, invc, mbuf, r);
            const float* Br = W + (size_t)r * PROJD * outd;
            if (relu && r == NR - 1)
                gemm_f32<true, false, true, false><<<g, 256, 0, stream>>>(
                    mbuf, PROJD, Br, outd, xout, outd, nullptr, nullptr, NN, outd, PROJD);
            else
                gemm_f32<true, false, false, false><<<g, 256, 0, stream>>>(
                    mbuf, PROJD, Br, outd, xout, outd, nullptr, nullptr, NN, outd, PROJD);
        }
    };
    layer(bufA, bufB, W0, root0, b0, HIDD, true);
    layer(bufB, bufA, W1, root1, b1, HIDD, true);
    layer(bufA, out, W2, root2, b2, OUTD, false);

    // --- decoder ---
    decoder<<<(2 * NE + 3) / 4, 256, 0, stream>>>(out, rele, src, dst, rel, nsrc, ndst, nrel,
                                                  scores, NE);
}

// Round 2
// 1410.115 us; speedup vs baseline: 2.9961x; 2.9961x over previous
//
#include <hip/hip_runtime.h>
#include <stdint.h>

#define NN 50000
#define NE 800000
#define NR 8
#define EMBD 512
#define PROJD 256
#define HIDD 256
#define OUTD 200
#define NSEG (NN * NR)

typedef _Float16 half8 __attribute__((ext_vector_type(8)));
typedef _Float16 half4 __attribute__((ext_vector_type(4)));
typedef float f32x4 __attribute__((ext_vector_type(4)));

// ---------------- async global->LDS (CK-style addrspace cast) ----------------
__device__ __forceinline__ void gload16(const void* g, void* l) {
    __builtin_amdgcn_global_load_lds(
        reinterpret_cast<const __attribute__((address_space(1))) uint32_t*>(
            reinterpret_cast<uintptr_t>(g)),
        reinterpret_cast<__attribute__((address_space(3))) uint32_t*>(
            reinterpret_cast<uintptr_t>(l)),
        16, 0, 0);
}

// ---------------- CSR build ----------------

__global__ void count_edges(const int* __restrict__ dst, const int* __restrict__ rel,
                            int* __restrict__ cnt, int E) {
    int e = blockIdx.x * 256 + threadIdx.x;
    if (e >= E) return;
    atomicAdd(&cnt[dst[e] * NR + rel[e]], 1);
}

__global__ __launch_bounds__(512) void scan1(const int* __restrict__ cnt, int* __restrict__ offs,
                                             int* __restrict__ bsums, int n) {
    __shared__ int sm[512];
    int tid = threadIdx.x;
    int g = blockIdx.x * 512 + tid;
    int v = (g < n) ? cnt[g] : 0;
    sm[tid] = v;
    __syncthreads();
    for (int o = 1; o < 512; o <<= 1) {
        int t = (tid >= o) ? sm[tid - o] : 0;
        __syncthreads();
        sm[tid] += t;
        __syncthreads();
    }
    if (g < n) offs[g] = sm[tid] - v;
    if (tid == 511) bsums[blockIdx.x] = sm[511];
}

__global__ __launch_bounds__(1024) void scan2(const int* __restrict__ bsums, int* __restrict__ bpref, int nb) {
    __shared__ int sm[1024];
    int tid = threadIdx.x;
    int v = (tid < nb) ? bsums[tid] : 0;
    sm[tid] = v;
    __syncthreads();
    for (int o = 1; o < 1024; o <<= 1) {
        int t = (tid >= o) ? sm[tid - o] : 0;
        __syncthreads();
        sm[tid] += t;
        __syncthreads();
    }
    if (tid < nb) bpref[tid] = sm[tid] - v;
}

__global__ __launch_bounds__(512) void scan3(int* __restrict__ offs, int* __restrict__ cursor,
                                             const int* __restrict__ bpref, int n, int total) {
    int g = blockIdx.x * 512 + threadIdx.x;
    if (g < n) {
        int v = offs[g] + bpref[blockIdx.x];
        offs[g] = v;
        cursor[g] = v;
    }
    if (g == 0) offs[n] = total;
}

__global__ void make_inv(const int* __restrict__ cnt, float* __restrict__ inv, int n) {
    int i = blockIdx.x * 256 + threadIdx.x;
    if (i >= n) return;
    int c = cnt[i];
    inv[i] = 1.0f / (float)(c > 1 ? c : 1);
}

__global__ void scatter_edges(const int* __restrict__ dst, const int* __restrict__ rel,
                              const int* __restrict__ src, int* __restrict__ cursor,
                              int* __restrict__ csr, int E) {
    int e = blockIdx.x * 256 + threadIdx.x;
    if (e >= E) return;
    int seg = dst[e] * NR + rel[e];
    int pos = atomicAdd(&cursor[seg], 1);
    csr[pos] = src[e];
}

// ---------------- converts ----------------

__global__ void f32_to_f16_vec(const float* __restrict__ in, _Float16* __restrict__ out, long n4) {
    long i = (long)blockIdx.x * 256 + threadIdx.x;
    long stride = (long)gridDim.x * 256;
    for (; i < n4; i += stride) {
        float4 v = ((const float4*)in)[i];
        half4 h;
        h[0] = (_Float16)v.x; h[1] = (_Float16)v.y; h[2] = (_Float16)v.z; h[3] = (_Float16)v.w;
        ((half4*)out)[i] = h;
    }
}

// Bt[n][k] = (k<K0 ? S0[k][n] : S1[k-K0][n]), fp32 -> fp16
__global__ void build_bt(const float* __restrict__ S0, int K0, const float* __restrict__ S1,
                         _Float16* __restrict__ Bt, int N, int K) {
    int k = blockIdx.x * 256 + threadIdx.x;
    int n = blockIdx.y;
    if (k >= K) return;
    float v = (k < K0) ? S0[(size_t)k * N + n] : S1[(size_t)(k - K0) * N + n];
    Bt[(size_t)n * K + k] = (_Float16)v;
}

// ---------------- segment mean, relations [r0,r1) -> abuf[NN][W] fp16 ----------------

__global__ __launch_bounds__(256) void segmean_chunk(
    const _Float16* __restrict__ x,      // [NN][256]
    const int* __restrict__ csr, const int* __restrict__ offs,
    const float* __restrict__ invc,
    _Float16* __restrict__ abuf, int W, int r0, int r1) {
    int wave = threadIdx.x >> 6, lane = threadIdx.x & 63;
    int d = blockIdx.x * 4 + wave;
    if (d >= NN) return;
    _Float16* arow = abuf + (size_t)d * W;
    int base = d * NR;
    for (int r = r0; r < r1; ++r) {
        int o0 = offs[base + r], o1 = offs[base + r + 1];
        float a0 = 0.f, a1 = 0.f, a2 = 0.f, a3 = 0.f;
        for (int j = o0; j < o1; ++j) {
            int s = csr[j];
            half4 v = *(const half4*)(x + (size_t)s * 256 + lane * 4);
            a0 += (float)v[0]; a1 += (float)v[1]; a2 += (float)v[2]; a3 += (float)v[3];
        }
        float ic = invc[base + r];
        half4 o;
        o[0] = (_Float16)(a0 * ic); o[1] = (_Float16)(a1 * ic);
        o[2] = (_Float16)(a2 * ic); o[3] = (_Float16)(a3 * ic);
        *(half4*)(arow + (size_t)(r - r0) * 256 + lane * 4) = o;
    }
}

// ---------------- fp16 MFMA GEMM: A[M][K] (lda=K) x Bt[N][.] -> epilogue ----------------
// 128x128 tile, BK=32, 256 threads (2x2 waves of 64x64), mfma 16x16x32 f16.

template <bool BIAS, bool ACC_IN, bool FINAL, bool RELU, bool LAST, bool SCATTER>
__global__ __launch_bounds__(256) void gemm16(
    const _Float16* __restrict__ A, int lda,
    const _Float16* __restrict__ Bt, int ldb,
    const float* __restrict__ bias, const int* __restrict__ sidx,
    float* __restrict__ Cacc, int ldacc,
    _Float16* __restrict__ C16, int ldc, float* __restrict__ C32,
    int M, int N, int K) {
    __shared__ _Float16 As[4096];  // [128][32]
    __shared__ _Float16 Bs[4096];  // [128][32]
    const int tid = threadIdx.x;
    const int lane = tid & 63, wave = tid >> 6;
    const int wm = wave >> 1, wn = wave & 1;
    const int q = lane >> 4, l15 = lane & 15;
    const int m0 = blockIdx.y * 128, n0 = blockIdx.x * 128;
    const int wbase = (tid & 192) * 8;  // wave LDS base (halves)
    f32x4 acc[4][4] = {};
    for (int k0 = 0; k0 < K; k0 += 32) {
        __syncthreads();
#pragma unroll
        for (int h = 0; h < 2; ++h) {
            int s = tid + h * 256;
            int r = s >> 2, c = s & 3;
            int cs = c ^ ((r >> 2) & 3);  // XOR-swizzled source chunk
            int ga = m0 + r;
            if (ga >= M) ga = 0;
            gload16(A + (size_t)ga * lda + k0 + cs * 8, &As[wbase + h * 2048]);
            int gb = n0 + r;
            if (gb >= N) gb = 0;
            gload16(Bt + (size_t)gb * ldb + k0 + cs * 8, &Bs[wbase + h * 2048]);
        }
        __syncthreads();
        half8 a[4], b[4];
#pragma unroll
        for (int i = 0; i < 4; ++i) {
            int row = wm * 64 + i * 16 + l15;
            a[i] = *(const half8*)&As[row * 32 + ((q ^ ((row >> 2) & 3)) << 3)];
            int col = wn * 64 + i * 16 + l15;
            b[i] = *(const half8*)&Bs[col * 32 + ((q ^ ((col >> 2) & 3)) << 3)];
        }
#pragma unroll
        for (int i = 0; i < 4; ++i)
#pragma unroll
            for (int j = 0; j < 4; ++j)
                acc[i][j] = __builtin_amdgcn_mfma_f32_16x16x32_f16(a[i], b[j], acc[i][j], 0, 0, 0);
    }
    // epilogue: C/D layout col=lane&15, row=(lane>>4)*4+t  [m89]
#pragma unroll
    for (int i = 0; i < 4; ++i) {
        int rbase = m0 + wm * 64 + i * 16 + q * 4;
#pragma unroll
        for (int j = 0; j < 4; ++j) {
            int cc = n0 + wn * 64 + j * 16 + l15;
            if (cc >= N) continue;
#pragma unroll
            for (int t = 0; t < 4; ++t) {
                int rr = rbase + t;
                if (rr >= M) continue;
                float v = acc[i][j][t];
                if (BIAS) v += bias[cc];
                if (ACC_IN) v += Cacc[(size_t)rr * ldacc + cc];
                if (!FINAL) {
                    Cacc[(size_t)rr * ldacc + cc] = v;
                } else {
                    if (RELU) v = fmaxf(v, 0.f);
                    int ro = SCATTER ? sidx[rr] : rr;
                    C16[(size_t)ro * ldc + cc] = (_Float16)v;
                    if (LAST) C32[(size_t)ro * ldc + cc] = v;
                }
            }
        }
    }
}

// ---------------- DistMult decoder (fp16 reads, 16 lanes/triple) ----------------

__global__ __launch_bounds__(256) void decoder16(
    const _Float16* __restrict__ out16, const _Float16* __restrict__ rel16,
    const int* __restrict__ src, const int* __restrict__ dst, const int* __restrict__ rel,
    const int* __restrict__ nsrc, const int* __restrict__ ndst, const int* __restrict__ nrel,
    float* __restrict__ scores) {
    int gid = blockIdx.x * 256 + threadIdx.x;
    int t = gid >> 4, lq = gid & 15;
    if (t >= 2 * NE) return;
    int s, o, r;
    if (t < NE) { s = src[t]; o = dst[t]; r = rel[t]; }
    else { int u = t - NE; s = nsrc[u]; o = ndst[u]; r = nrel[u]; }
    const half8* ps = (const half8*)(out16 + (size_t)s * OUTD);
    const half8* po = (const half8*)(out16 + (size_t)o * OUTD);
    const half8* pr = (const half8*)(rel16 + (size_t)r * OUTD);
    float acc = 0.f;
#pragma unroll
    for (int it = 0; it < 2; ++it) {
        int c = it * 16 + lq;
        if (c < 25) {
            half8 a = ps[c], b = pr[c], d = po[c];
#pragma unroll
            for (int u = 0; u < 8; ++u) acc += (float)a[u] * (float)b[u] * (float)d[u];
        }
    }
#pragma unroll
    for (int off = 8; off; off >>= 1) acc += __shfl_xor(acc, off);
    if (lq == 0) scores[t] = acc;
}

// ---------------- host ----------------

extern "C" void kernel_launch(void* const* d_in, const int* in_sizes, int n_in,
                              void* d_out, int out_size, void* d_ws, size_t ws_size,
                              hipStream_t stream) {
    const float* emb   = (const float*)d_in[0];
    const int*   nidx  = (const int*)d_in[1];
    const int*   src   = (const int*)d_in[2];
    const int*   dst   = (const int*)d_in[3];
    const int*   rel   = (const int*)d_in[4];
    const int*   nsrc  = (const int*)d_in[5];
    const int*   ndst  = (const int*)d_in[6];
    const int*   nrel  = (const int*)d_in[7];
    const float* Wp    = (const float*)d_in[8];
    const float* bp    = (const float*)d_in[9];
    const float* W0    = (const float*)d_in[10];
    const float* root0 = (const float*)d_in[11];
    const float* b0    = (const float*)d_in[12];
    const float* W1    = (const float*)d_in[13];
    const float* root1 = (const float*)d_in[14];
    const float* b1    = (const float*)d_in[15];
    const float* W2    = (const float*)d_in[16];
    const float* root2 = (const float*)d_in[17];
    const float* b2    = (const float*)d_in[18];
    const float* rele  = (const float*)d_in[19];
    (void)in_sizes; (void)n_in; (void)out_size;

    float* out    = (float*)d_out;            // [NN][OUTD]
    float* scores = out + (size_t)NN * OUTD;  // [2*NE]

    auto align = [](size_t x) { return (x + 255) & ~(size_t)255; };
    const size_t sz_emb16 = align((size_t)NN * EMBD * 2);
    const size_t sz_xbuf  = align((size_t)NN * 256 * 2);
    const size_t sz_cacc  = align((size_t)NN * 256 * 4);
    const size_t sz_bt    = align((size_t)256 * 2304 * 2);
    const size_t sz_btp   = align((size_t)256 * EMBD * 2);
    const size_t sz_rel16 = align((size_t)NR * OUTD * 2);
    const size_t sz_segi  = align((size_t)NSEG * 4);
    const size_t sz_offs  = align((size_t)(NSEG + 1) * 4);
    const size_t sz_csr   = align((size_t)NE * 4);
    const size_t sz_small = align(4096);

    // pick largest relation-chunk RC whose layout fits ws_size (deterministic)
    int RC = 16;
    size_t sz_abuf, region;
    do {
        RC >>= 1;
        sz_abuf = align((size_t)NN * RC * 256 * 2);
        region = sz_abuf + sz_cacc;
        if (region < sz_emb16) region = sz_emb16;
        size_t total = region + 2 * sz_xbuf + 3 * sz_bt + sz_btp + sz_rel16 +
                       3 * sz_segi + sz_offs + sz_csr + 2 * sz_small;
        if (total <= ws_size || RC == 1) break;
    } while (RC > 1);

    char* p = (char*)d_ws;
    _Float16* emb16 = (_Float16*)p;               // dead after proj
    _Float16* abuf  = (_Float16*)p;               // live from L0 on
    float*    Cacc  = (float*)(p + sz_abuf);      // live from L0 on
    p += region;
    _Float16* xbufA = (_Float16*)p; p += sz_xbuf;
    _Float16* xbufB = (_Float16*)p;               // shared with out16 (xbufB dead in L2)
    _Float16* out16 = xbufB; p += sz_xbuf;
    _Float16* Bt0 = (_Float16*)p; p += sz_bt;
    _Float16* Bt1 = (_Float16*)p; p += sz_bt;
    _Float16* Bt2 = (_Float16*)p; p += sz_bt;
    _Float16* BtP = (_Float16*)p; p += sz_btp;
    _Float16* rel16 = (_Float16*)p; p += sz_rel16;
    int*   cnt    = (int*)p; p += sz_segi;
    float* invc   = (float*)p; p += sz_segi;
    int*   cursor = (int*)p; p += sz_segi;
    int*   offs   = (int*)p; p += sz_offs;
    int*   csr    = (int*)p; p += sz_csr;
    int*   bsums  = (int*)p; p += sz_small;
    int*   bpref  = (int*)p; p += sz_small;

    // --- CSR build ---
    hipMemsetAsync(cnt, 0, (size_t)NSEG * 4, stream);
    count_edges<<<(NE + 255) / 256, 256, 0, stream>>>(dst, rel, cnt, NE);
    const int NB = (NSEG + 511) / 512;
    scan1<<<NB, 512, 0, stream>>>(cnt, offs, bsums, NSEG);
    scan2<<<1, 1024, 0, stream>>>(bsums, bpref, NB);
    scan3<<<NB, 512, 0, stream>>>(offs, cursor, bpref, NSEG, NE);
    make_inv<<<(NSEG + 255) / 256, 256, 0, stream>>>(cnt, invc, NSEG);
    scatter_edges<<<(NE + 255) / 256, 256, 0, stream>>>(dst, rel, src, cursor, csr, NE);

    // --- weight/embedding converts ---
    f32_to_f16_vec<<<2048, 256, 0, stream>>>(emb, emb16, (long)NN * EMBD / 4);
    f32_to_f16_vec<<<2, 256, 0, stream>>>(rele, rel16, (long)NR * OUTD / 4);
    build_bt<<<dim3(2, 256), 256, 0, stream>>>(Wp, EMBD, nullptr, BtP, PROJD, EMBD);
    build_bt<<<dim3(9, 256), 256, 0, stream>>>(root0, 256, W0, Bt0, HIDD, 2304);
    build_bt<<<dim3(9, 256), 256, 0, stream>>>(root1, 256, W1, Bt1, HIDD, 2304);
    build_bt<<<dim3(9, 200), 256, 0, stream>>>(root2, 256, W2, Bt2, OUTD, 2304);

    // --- projection: xbufA[nidx[i]] = fp16(emb[i] @ Wp + bp) ---
    hipMemsetAsync(xbufA, 0, (size_t)NN * 256 * 2, stream);
    {
        dim3 g(2, (NN + 127) / 128);
        gemm16<true, false, true, false, false, true><<<g, 256, 0, stream>>>(
            emb16, EMBD, BtP, EMBD, bp, nidx, nullptr, 0, xbufA, 256, nullptr, NN, 256, EMBD);
    }

    // --- RGCN layers ---
    auto run_layer = [&](const _Float16* xin, _Float16* xo16, float* xo32,
                         const _Float16* BtL, const float* bias, int N_, bool last) {
        dim3 g((N_ + 127) / 128, (NN + 127) / 128);
        // root: Cacc = xin @ root + bias
        gemm16<true, false, false, false, false, false><<<g, 256, 0, stream>>>(
            xin, 256, BtL, 2304, bias, nullptr, Cacc, 256, nullptr, 0, nullptr, NN, N_, 256);
        int nch = NR / RC;
        for (int c = 0; c < nch; ++c) {
            int r0 = c * RC;
            segmean_chunk<<<(NN + 3) / 4, 256, 0, stream>>>(xin, csr, offs, invc, abuf,
                                                            RC * 256, r0, r0 + RC);
            const _Float16* Bc = BtL + 256 + r0 * 256;
            bool fin = (c == nch - 1);
            if (!fin)
                gemm16<false, true, false, false, false, false><<<g, 256, 0, stream>>>(
                    abuf, RC * 256, Bc, 2304, nullptr, nullptr, Cacc, 256, nullptr, 0, nullptr,
                    NN, N_, RC * 256);
            else if (!last)
                gemm16<false, true, true, true, false, false><<<g, 256, 0, stream>>>(
                    abuf, RC * 256, Bc, 2304, nullptr, nullptr, Cacc, 256, xo16, 256, nullptr,
                    NN, N_, RC * 256);
            else
                gemm16<false, true, true, false, true, false><<<g, 256, 0, stream>>>(
                    abuf, RC * 256, Bc, 2304, nullptr, nullptr, Cacc, 256, xo16, OUTD, xo32,
                    NN, N_, RC * 256);
        }
    };
    run_layer(xbufA, xbufB, nullptr, Bt0, b0, HIDD, false);
    run_layer(xbufB, xbufA, nullptr, Bt1, b1, HIDD, false);
    run_layer(xbufA, out16, out, Bt2, b2, OUTD, true);

    // --- decoder ---
    decoder16<<<(2 * NE * 16 + 255) / 256, 256, 0, stream>>>(out16, rel16, src, dst, rel,
                                                             nsrc, ndst, nrel, scores);
}